// Round 8
// baseline (324.915 us; speedup 1.0000x reference)
//
#include <hip/hip_runtime.h>
#include <stdint.h>

typedef __bf16 bf16;
typedef __bf16 bf16x4 __attribute__((ext_vector_type(4)));
typedef __bf16 bf16x8 __attribute__((ext_vector_type(8)));
typedef float  fx4    __attribute__((ext_vector_type(4)));

#define MFMA16(a, b, c) __builtin_amdgcn_mfma_f32_16x16x32_bf16((a), (b), (c), 0, 0, 0)

// B=4, N=2048, E=768, H=8, D=96; M = B*N = 8192. User tensors fp32, out fp32.

// ---------------------------------------------------------------------------
// Barrier WITHOUT the vmem drain (lgkmcnt(0) only). Keeps global_load_lds
// DMA in flight across barriers. 0xC07F = vmcnt 63 (nowait), exp 7, lgkm 0.
// ---------------------------------------------------------------------------
__device__ __forceinline__ void barrier_nodrain() {
  __asm__ __volatile__("" ::: "memory");
  __builtin_amdgcn_s_waitcnt(0xC07F);
  __builtin_amdgcn_s_barrier();
  __asm__ __volatile__("" ::: "memory");
}

// Counted vmem wait: vmcnt(6) — wait oldest loads, allow 6 newest in flight.
__device__ __forceinline__ void wait_vm6() {
  __asm__ __volatile__("" ::: "memory");
  __builtin_amdgcn_s_waitcnt(0x0F76);
  __asm__ __volatile__("" ::: "memory");
}
// lgkmcnt(0) only (LDS reads retired; region safe to overwrite).
__device__ __forceinline__ void wait_lgkm0() {
  __asm__ __volatile__("" ::: "memory");
  __builtin_amdgcn_s_waitcnt(0xC07F);
  __asm__ __volatile__("" ::: "memory");
}

// DMA 16 B/lane global -> LDS (dest = wave-uniform base + lane*16, m104).
__device__ __forceinline__ void gload_lds16(const void* g, void* l) {
  __builtin_amdgcn_global_load_lds(
      (const __attribute__((address_space(1))) void*)g,
      (__attribute__((address_space(3))) void*)l, 16, 0, 0);
}

// ---------------------------------------------------------------------------
// x (fp32) -> bf16, 4 elems/thread.
// ---------------------------------------------------------------------------
__global__ __launch_bounds__(256)
void cvt_x_kernel(const float* __restrict__ x, bf16* __restrict__ xb) {
  const int i = (blockIdx.x * 256 + threadIdx.x) * 4;
  float4 v = *(const float4*)&x[i];
  bf16x4 o;
  o[0] = (bf16)v.x; o[1] = (bf16)v.y; o[2] = (bf16)v.z; o[3] = (bf16)v.w;
  *(bf16x4*)&xb[i] = o;
}

// ---------------------------------------------------------------------------
// Fused QKV GEMM (R17, proven): A DMA double-buffered, B coalesced reg-staged.
// K/V outputs in attention-staging tile layout:
//   K: [b][h][kt][u=d/8][k32][d%8]   V: [b][h][kt][ku=k/8][d96][k%8]
// ---------------------------------------------------------------------------
__global__ __launch_bounds__(256)
void gemm_qkv(const bf16* __restrict__ A,
              const float* __restrict__ Wq, const float* __restrict__ Wk,
              const float* __restrict__ Wv,
              const float* __restrict__ bq, const float* __restrict__ bk,
              const float* __restrict__ bv,
              bf16* __restrict__ Qo, bf16* __restrict__ Ka,
              bf16* __restrict__ Va) {
  constexpr int K = 768;
  __shared__ __align__(16) bf16 As[2][128 * 32];
  __shared__ __align__(16) bf16 Bs[128 * 32];

  const int tid  = threadIdx.x;
  const int wave = tid >> 6;
  const int lane = tid & 63;
  const int l15  = lane & 15;
  const int q4   = lane >> 4;
  const int wr   = wave >> 1;
  const int wc   = wave & 1;
  const int sel  = blockIdx.x / 6;
  const int cb0  = (blockIdx.x % 6) * 128;
  const int rb0  = blockIdx.y * 128;

  const float* W   = (sel == 0) ? Wq : (sel == 1) ? Wk : Wv;
  const float* bia = (sel == 0) ? bq : (sel == 1) ? bk : bv;

  const int ar0 = tid >> 2,         akc0 = (tid & 3) << 3;
  const int ar1 = ar0 + 64,         akc1 = akc0;

  fx4 acc[4][4];
#pragma unroll
  for (int i = 0; i < 4; i++)
#pragma unroll
    for (int j = 0; j < 4; j++) acc[i][j] = (fx4){0.f, 0.f, 0.f, 0.f};

  gload_lds16(&A[(size_t)(rb0 + ar0) * K + akc0], &As[0][wave * 512]);
  gload_lds16(&A[(size_t)(rb0 + ar1) * K + akc1], &As[0][(wave + 4) * 512]);

  int cur = 0;
  for (int k0 = 0; k0 < K; k0 += 32, cur ^= 1) {
    const float* wp0 = W + (size_t)(cb0 + ar0) * K + k0 + akc0;
    const float* wp1 = W + (size_t)(cb0 + ar1) * K + k0 + akc1;
    const float4 b0a = *(const float4*)wp0;
    const float4 b0b = *(const float4*)(wp0 + 4);
    const float4 b1a = *(const float4*)wp1;
    const float4 b1b = *(const float4*)(wp1 + 4);
    __asm__ __volatile__("" ::: "memory");

    const int kn = (k0 + 32 < K) ? k0 + 32 : k0;
    gload_lds16(&A[(size_t)(rb0 + ar0) * K + kn + akc0],
                &As[cur ^ 1][wave * 512]);
    gload_lds16(&A[(size_t)(rb0 + ar1) * K + kn + akc1],
                &As[cur ^ 1][(wave + 4) * 512]);
    __asm__ __volatile__("" ::: "memory");

    bf16x8 pb0, pb1;
    pb0[0] = (bf16)b0a.x; pb0[1] = (bf16)b0a.y;
    pb0[2] = (bf16)b0a.z; pb0[3] = (bf16)b0a.w;
    pb0[4] = (bf16)b0b.x; pb0[5] = (bf16)b0b.y;
    pb0[6] = (bf16)b0b.z; pb0[7] = (bf16)b0b.w;
    pb1[0] = (bf16)b1a.x; pb1[1] = (bf16)b1a.y;
    pb1[2] = (bf16)b1a.z; pb1[3] = (bf16)b1a.w;
    pb1[4] = (bf16)b1b.x; pb1[5] = (bf16)b1b.y;
    pb1[6] = (bf16)b1b.z; pb1[7] = (bf16)b1b.w;
    *(bf16x8*)&Bs[ar0 * 32 + akc0] = pb0;
    *(bf16x8*)&Bs[ar1 * 32 + akc1] = pb1;

    barrier_nodrain();

    bf16x8 a[4], b[4];
#pragma unroll
    for (int i = 0; i < 4; i++)
      a[i] = *(const bf16x8*)&As[cur][(wr * 64 + i * 16 + l15) * 32 + q4 * 8];
#pragma unroll
    for (int j = 0; j < 4; j++)
      b[j] = *(const bf16x8*)&Bs[(wc * 64 + j * 16 + l15) * 32 + q4 * 8];
#pragma unroll
    for (int i = 0; i < 4; i++)
#pragma unroll
      for (int j = 0; j < 4; j++)
        acc[i][j] = MFMA16(a[i], b[j], acc[i][j]);

    barrier_nodrain();
  }

  const int cb = cb0 + wc * 64;
  const int rb = rb0 + wr * 64;
#pragma unroll
  for (int j = 0; j < 4; j++) {
    const int o  = cb + j * 16 + l15;
    const float bj = bia[o];
    const int hh = o / 96;
    const int dd = o - hh * 96;
#pragma unroll
    for (int i = 0; i < 4; i++) {
      const int r0 = rb + i * 16 + q4 * 4;
      if (sel == 2) {
        const int bb = r0 >> 11;
        const int n2 = r0 & 2047;
        const size_t flat =
            ((size_t)((bb * 8 + hh) * 64 + (n2 >> 5))) * 3072 +
            ((n2 >> 3) & 3) * 768 + dd * 8 + (n2 & 7);
        bf16x4 pk;
#pragma unroll
        for (int r = 0; r < 4; r++) pk[r] = (bf16)(acc[i][j][r] + bj);
        *(bf16x4*)&Va[flat] = pk;
      } else if (sel == 1) {
        const int u  = dd >> 3;
        const int de = dd & 7;
#pragma unroll
        for (int r = 0; r < 4; r++) {
          const int n  = r0 + r;
          const int bb = n >> 11;
          const int n2 = n & 2047;
          const size_t flat =
              ((size_t)((bb * 8 + hh) * 64 + (n2 >> 5))) * 3072 +
              u * 256 + (n2 & 31) * 8 + de;
          Ka[flat] = (bf16)(acc[i][j][r] + bj);
        }
      } else {
#pragma unroll
        for (int r = 0; r < 4; r++)
          Qo[(size_t)(r0 + r) * 768 + o] = (bf16)(acc[i][j][r] + bj);
      }
    }
  }
}

// ---------------------------------------------------------------------------
// Output projection: out[M,768] fp32 = AO bf16 @ Wo^T + bo (R17, proven).
// ---------------------------------------------------------------------------
__global__ __launch_bounds__(256)
void gemm_o(const bf16* __restrict__ A, const float* __restrict__ W,
            const float* __restrict__ bias, float* __restrict__ C) {
  constexpr int K = 768;
  __shared__ __align__(16) bf16 As[2][128 * 32];
  __shared__ __align__(16) bf16 Bs[128 * 32];

  const int tid  = threadIdx.x;
  const int wave = tid >> 6;
  const int lane = tid & 63;
  const int l15  = lane & 15;
  const int q4   = lane >> 4;
  const int wr   = wave >> 1;
  const int wc   = wave & 1;
  const int rb0  = blockIdx.y * 128;
  const int cb0  = blockIdx.x * 128;

  const int ar0 = tid >> 2,         akc0 = (tid & 3) << 3;
  const int ar1 = ar0 + 64,         akc1 = akc0;

  fx4 acc[4][4];
#pragma unroll
  for (int i = 0; i < 4; i++)
#pragma unroll
    for (int j = 0; j < 4; j++) acc[i][j] = (fx4){0.f, 0.f, 0.f, 0.f};

  gload_lds16(&A[(size_t)(rb0 + ar0) * K + akc0], &As[0][wave * 512]);
  gload_lds16(&A[(size_t)(rb0 + ar1) * K + akc1], &As[0][(wave + 4) * 512]);

  int cur = 0;
  for (int k0 = 0; k0 < K; k0 += 32, cur ^= 1) {
    const float* wp0 = W + (size_t)(cb0 + ar0) * K + k0 + akc0;
    const float* wp1 = W + (size_t)(cb0 + ar1) * K + k0 + akc1;
    const float4 b0a = *(const float4*)wp0;
    const float4 b0b = *(const float4*)(wp0 + 4);
    const float4 b1a = *(const float4*)wp1;
    const float4 b1b = *(const float4*)(wp1 + 4);
    __asm__ __volatile__("" ::: "memory");

    const int kn = (k0 + 32 < K) ? k0 + 32 : k0;
    gload_lds16(&A[(size_t)(rb0 + ar0) * K + kn + akc0],
                &As[cur ^ 1][wave * 512]);
    gload_lds16(&A[(size_t)(rb0 + ar1) * K + kn + akc1],
                &As[cur ^ 1][(wave + 4) * 512]);
    __asm__ __volatile__("" ::: "memory");

    bf16x8 pb0, pb1;
    pb0[0] = (bf16)b0a.x; pb0[1] = (bf16)b0a.y;
    pb0[2] = (bf16)b0a.z; pb0[3] = (bf16)b0a.w;
    pb0[4] = (bf16)b0b.x; pb0[5] = (bf16)b0b.y;
    pb0[6] = (bf16)b0b.z; pb0[7] = (bf16)b0b.w;
    pb1[0] = (bf16)b1a.x; pb1[1] = (bf16)b1a.y;
    pb1[2] = (bf16)b1a.z; pb1[3] = (bf16)b1a.w;
    pb1[4] = (bf16)b1b.x; pb1[5] = (bf16)b1b.y;
    pb1[6] = (bf16)b1b.z; pb1[7] = (bf16)b1b.w;
    *(bf16x8*)&Bs[ar0 * 32 + akc0] = pb0;
    *(bf16x8*)&Bs[ar1 * 32 + akc1] = pb1;

    barrier_nodrain();

    bf16x8 a[4], b[4];
#pragma unroll
    for (int i = 0; i < 4; i++)
      a[i] = *(const bf16x8*)&As[cur][(wr * 64 + i * 16 + l15) * 32 + q4 * 8];
#pragma unroll
    for (int j = 0; j < 4; j++)
      b[j] = *(const bf16x8*)&Bs[(wc * 64 + j * 16 + l15) * 32 + q4 * 8];
#pragma unroll
    for (int i = 0; i < 4; i++)
#pragma unroll
      for (int j = 0; j < 4; j++)
        acc[i][j] = MFMA16(a[i], b[j], acc[i][j]);

    barrier_nodrain();
  }

  const int cb = cb0 + wc * 64;
  const int rb = rb0 + wr * 64;
#pragma unroll
  for (int j = 0; j < 4; j++) {
    const int o  = cb + j * 16 + l15;
    const float bj = bias[o];
#pragma unroll
    for (int i = 0; i < 4; i++) {
      const int r0 = rb + i * 16 + q4 * 4;
#pragma unroll
      for (int r = 0; r < 4; r++)
        C[(size_t)(r0 + r) * 768 + o] = acc[i][j][r] + bj;
    }
  }
}

// ---------------------------------------------------------------------------
// Attention, softmax over HEADS (dim=1), / sqrt(768).
// R18 = R15 DMA staging + INTRA-ITERATION PHASE OVERLAP:
//   old body: QK^T -> scatter -> bar -> softmax -> bar -> PV   (each region
//   single-role: MFMA idle during softmax's ~300-cyc latency chain, VALU
//   idle during MFMA; 1 block/CU -> nothing else fills the gaps).
//   new body (same 2 barriers, same LDS):
//     region1: readK(kt+1), stageK(kt+2), QK^T(kt+1) || softmax(kt)
//     region2: readV(kt), readP(kt), stageV(kt+1), scatter(kt+1) || PV(kt)
//   Legality: QK^T(kt+1) independent of softmax(kt) (regs+Kl vs Ebuf).
//   scatter(kt+1) vs PV(kt): same wave reads its P-frags BEFORE scattering
//   its own head's columns (per-wave LDS ops execute in order); waves only
//   touch their own head's columns in region2, all-column softmax stays
//   barrier-separated. Uniform loop via clamped redundant staging/compute
//   at kt=63 (re-scatter of E(63) after P-reads: benign overwrite).
//   s_setprio(1) around MFMA clusters (T5).
// vmcnt discipline: each region-entry wait_vm6 drains exactly the older
// 6-load group (FIFO), verified for prologue, steady state, and tail.
// LDS: Kbuf 48 + Vbuf 48 + Ebuf 32.5 = 128.5 KB (1 block/CU).
// Go/no-go: WRITE_SIZE stays ~12 MB (no spill); attn < 130 µs.
// ---------------------------------------------------------------------------
__global__ __launch_bounds__(512, 1)
void attn_kernel(const bf16* Q, const bf16* __restrict__ Ka,
                 const bf16* __restrict__ Va, bf16* AO) {
  __shared__ __align__(16) bf16  Kbuf[8 * 3072];   // [h][u12][k32][8] 48 KB
  __shared__ __align__(16) bf16  Vbuf[8 * 3072];   // [h][ku4][d96][8] 48 KB
  __shared__ __align__(16) float Ebuf[32 * 260];   // [q][h*32+k]    32.5 KB

  const int tid  = threadIdx.x;
  const int h    = tid >> 6;
  const int lane = tid & 63;
  const int l15  = lane & 15;
  const int q4   = lane >> 4;
  const int b    = blockIdx.x >> 6;
  const int qt   = blockIdx.x & 63;
  const int qrow0 = b * 2048 + qt * 32;

  // Persistent Q fragments: 2 q-16tiles x 3 d-chunks.
  bf16x8 aq[2][3];
#pragma unroll
  for (int i = 0; i < 2; i++)
#pragma unroll
    for (int c = 0; c < 3; c++)
      aq[i][c] = *(const bf16x8*)
          &Q[(size_t)(qrow0 + i * 16 + l15) * 768 + h * 96 + c * 32 + q4 * 8];

  fx4 o[2][6];
#pragma unroll
  for (int i = 0; i < 2; i++)
#pragma unroll
    for (int j = 0; j < 6; j++) o[i][j] = (fx4){0.f, 0.f, 0.f, 0.f};

  const bf16* Kt0 = Ka + (size_t)(b * 8 + h) * 64 * 3072;
  const bf16* Vt0 = Va + (size_t)(b * 8 + h) * 64 * 3072;
  bf16* Kl = &Kbuf[h * 3072];
  bf16* Vl = &Vbuf[h * 3072];

  auto stageK = [&](int kt) {
    const bf16* src = Kt0 + (size_t)kt * 3072 + lane * 8;
#pragma unroll
    for (int t = 0; t < 6; t++)
      gload_lds16(src + t * 512, Kl + t * 512);
  };
  auto stageV = [&](int kt) {
    const bf16* src = Vt0 + (size_t)kt * 3072 + lane * 8;
#pragma unroll
    for (int t = 0; t < 6; t++)
      gload_lds16(src + t * 512, Vl + t * 512);
  };

  bf16x8 bk[2][3];
  auto readK = [&]() {
#pragma unroll
    for (int j = 0; j < 2; j++)
#pragma unroll
      for (int c = 0; c < 3; c++)
        bk[j][c] =
            *(const bf16x8*)&Kl[(c * 4 + q4) * 256 + (j * 16 + l15) * 8];
  };

  fx4 e[2][2];
  auto qkt = [&]() {
    e[0][0] = e[0][1] = e[1][0] = e[1][1] = (fx4){0.f, 0.f, 0.f, 0.f};
    __builtin_amdgcn_s_setprio(1);
#pragma unroll
    for (int c = 0; c < 3; c++)
#pragma unroll
      for (int j = 0; j < 2; j++) {
        e[0][j] = MFMA16(aq[0][c], bk[j][c], e[0][j]);
        e[1][j] = MFMA16(aq[1][c], bk[j][c], e[1][j]);
      }
    __builtin_amdgcn_s_setprio(0);
  };
  auto scatterE = [&]() {
#pragma unroll
    for (int i = 0; i < 2; i++)
#pragma unroll
      for (int j = 0; j < 2; j++)
#pragma unroll
        for (int r = 0; r < 4; r++)
          Ebuf[(i * 16 + q4 * 4 + r) * 260 + h * 32 + j * 16 + l15] =
              e[i][j][r];
  };

  // ---- Prologue: establish steady-state [K(kt+1) older, V(kt) newer] ----
  stageK(0);
  __builtin_amdgcn_s_waitcnt(0x0070);  // drain: K(0) + aq loads landed
  readK();                             // bk = K(0)
  wait_lgkm0();
  stageK(1);                           // out: K(1)
  stageV(0);                           // out: K(1), V(0)  (K older ✓)
  qkt();                               // e = E(0)
  scatterE();                          // Ebuf = E(0)
  barrier_nodrain();

  for (int kt = 0; kt < 64; kt++) {
    // ---- region 1: softmax(kt) || QK^T(kt+1) ----
    wait_vm6();          // drains K(kt+1) (older), leaves V(kt) in flight
    readK();             // bk = K(kt+1)
    wait_lgkm0();
    stageK(kt + 2 < 64 ? kt + 2 : 63);
    qkt();               // e = E(kt+1)   (MFMA, overlaps softmax below)

    // Softmax over heads, IN PLACE (f32). 1024 (q,k) pairs, 2 per thread.
#pragma unroll
    for (int pp = 0; pp < 2; pp++) {
      const int p = tid + pp * 512;
      const int q = p >> 5, k = p & 31;
      float* row = &Ebuf[q * 260 + k];
      float v[8];
#pragma unroll
      for (int hh = 0; hh < 8; hh++) v[hh] = row[hh * 32];
      float m = v[0];
#pragma unroll
      for (int hh = 1; hh < 8; hh++) m = fmaxf(m, v[hh]);
      float sm = 0.f;
#pragma unroll
      for (int hh = 0; hh < 8; hh++) { v[hh] = __expf(v[hh] - m); sm += v[hh]; }
      const float inv = 1.0f / (sm * 27.712812921102035f);  // / sqrt(768)
#pragma unroll
      for (int hh = 0; hh < 8; hh++) row[hh * 32] = v[hh] * inv;
    }
    barrier_nodrain();

    // ---- region 2: PV(kt) || scatter(kt+1) ----
    wait_vm6();          // drains V(kt) (older), leaves K(kt+2) in flight

    bf16x8 bv[6];
#pragma unroll
    for (int j2 = 0; j2 < 6; j2++)
      bv[j2] = *(const bf16x8*)&Vl[q4 * 768 + (j2 * 16 + l15) * 8];

    // P frags from Ebuf f32 -> bf16 (read BEFORE scatter: per-wave in-order).
    bf16x8 ap[2];
#pragma unroll
    for (int i = 0; i < 2; i++) {
      const float* ps = &Ebuf[(i * 16 + l15) * 260 + h * 32 + q4 * 8];
      fx4 p0 = *(const fx4*)ps;
      fx4 p1 = *(const fx4*)(ps + 4);
      bf16x8 t;
      t[0] = (bf16)p0[0]; t[1] = (bf16)p0[1];
      t[2] = (bf16)p0[2]; t[3] = (bf16)p0[3];
      t[4] = (bf16)p1[0]; t[5] = (bf16)p1[1];
      t[6] = (bf16)p1[2]; t[7] = (bf16)p1[3];
      ap[i] = t;
    }
    wait_lgkm0();        // bv + ap retired; Vl free
    stageV(kt + 1 < 64 ? kt + 1 : 63);

    scatterE();          // E(kt+1) -> own head columns (LDS writes)

    __builtin_amdgcn_s_setprio(1);
#pragma unroll
    for (int j2 = 0; j2 < 6; j2++) {
      o[0][j2] = MFMA16(ap[0], bv[j2], o[0][j2]);
      o[1][j2] = MFMA16(ap[1], bv[j2], o[1][j2]);
    }
    __builtin_amdgcn_s_setprio(0);
    barrier_nodrain();
  }

  // Drain outstanding DMA before exit/stores.
  __builtin_amdgcn_s_waitcnt(0x0070);

  // Write AO[qrow0 + q][h*96 + d]
#pragma unroll
  for (int i = 0; i < 2; i++)
#pragma unroll
    for (int j2 = 0; j2 < 6; j2++)
#pragma unroll
      for (int r = 0; r < 4; r++)
        AO[(size_t)(qrow0 + i * 16 + q4 * 4 + r) * 768 + h * 96 + j2 * 16 + l15] =
            (bf16)(o[i][j2][r]);
}

// ---------------------------------------------------------------------------
// Memory plan: d_out = xb + Ka (both dead before gemm_o overwrites d_out).
// ws = Q + Va (25.2 MB). AO aliases Q.
// ---------------------------------------------------------------------------
extern "C" void kernel_launch(void* const* d_in, const int* in_sizes, int n_in,
                              void* d_out, int out_size, void* d_ws,
                              size_t ws_size, hipStream_t stream) {
  const float* x  = (const float*)d_in[0];
  const float* Wq = (const float*)d_in[1];
  const float* bq = (const float*)d_in[2];
  const float* Wk = (const float*)d_in[3];
  const float* bk = (const float*)d_in[4];
  const float* Wv = (const float*)d_in[5];
  const float* bv = (const float*)d_in[6];
  const float* Wo = (const float*)d_in[7];
  const float* bo = (const float*)d_in[8];

  const size_t MN = (size_t)8192 * 768;
  bf16* xb = (bf16*)d_out;
  bf16* Ka = xb + MN;
  bf16* Q  = (bf16*)d_ws;
  bf16* Va = Q + MN;
  bf16* AO = Q;  // aliases Q

  cvt_x_kernel<<<6144, 256, 0, stream>>>(x, xb);
  dim3 qkvgrid(18, 64);
  gemm_qkv<<<qkvgrid, 256, 0, stream>>>(xb, Wq, Wk, Wv, bq, bk, bv, Q, Ka, Va);
  attn_kernel<<<256, 512, 0, stream>>>(Q, Ka, Va, AO);
  dim3 ogrid(6, 64);
  gemm_o<<<ogrid, 256, 0, stream>>>(AO, Wo, bo, (float*)d_out);
}

// Round 9
// 313.876 us; speedup vs baseline: 1.0352x; 1.0352x over previous
//
#include <hip/hip_runtime.h>
#include <stdint.h>

typedef __bf16 bf16;
typedef __bf16 bf16x2 __attribute__((ext_vector_type(2)));
typedef __bf16 bf16x4 __attribute__((ext_vector_type(4)));
typedef __bf16 bf16x8 __attribute__((ext_vector_type(8)));
typedef float  fx2    __attribute__((ext_vector_type(2)));
typedef float  fx4    __attribute__((ext_vector_type(4)));

#define MFMA16(a, b, c) __builtin_amdgcn_mfma_f32_16x16x32_bf16((a), (b), (c), 0, 0, 0)

// B=4, N=2048, E=768, H=8, D=96; M = B*N = 8192. User tensors fp32, out fp32.

// ---------------------------------------------------------------------------
// Barrier WITHOUT the vmem drain (lgkmcnt(0) only). Keeps global_load_lds
// DMA in flight across barriers. 0xC07F = vmcnt 63 (nowait), exp 7, lgkm 0.
// ---------------------------------------------------------------------------
__device__ __forceinline__ void barrier_nodrain() {
  __asm__ __volatile__("" ::: "memory");
  __builtin_amdgcn_s_waitcnt(0xC07F);
  __builtin_amdgcn_s_barrier();
  __asm__ __volatile__("" ::: "memory");
}

// Counted vmem wait: vmcnt(6) — wait oldest loads, allow 6 newest in flight.
__device__ __forceinline__ void wait_vm6() {
  __asm__ __volatile__("" ::: "memory");
  __builtin_amdgcn_s_waitcnt(0x0F76);
  __asm__ __volatile__("" ::: "memory");
}
// lgkmcnt(0) only (LDS reads retired; region safe to overwrite).
__device__ __forceinline__ void wait_lgkm0() {
  __asm__ __volatile__("" ::: "memory");
  __builtin_amdgcn_s_waitcnt(0xC07F);
  __asm__ __volatile__("" ::: "memory");
}

// DMA 16 B/lane global -> LDS (dest = wave-uniform base + lane*16, m104).
__device__ __forceinline__ void gload_lds16(const void* g, void* l) {
  __builtin_amdgcn_global_load_lds(
      (const __attribute__((address_space(1))) void*)g,
      (__attribute__((address_space(3))) void*)l, 16, 0, 0);
}

// ---------------------------------------------------------------------------
// x (fp32) -> bf16, 4 elems/thread.
// ---------------------------------------------------------------------------
__global__ __launch_bounds__(256)
void cvt_x_kernel(const float* __restrict__ x, bf16* __restrict__ xb) {
  const int i = (blockIdx.x * 256 + threadIdx.x) * 4;
  float4 v = *(const float4*)&x[i];
  bf16x4 o;
  o[0] = (bf16)v.x; o[1] = (bf16)v.y; o[2] = (bf16)v.z; o[3] = (bf16)v.w;
  *(bf16x4*)&xb[i] = o;
}

// ---------------------------------------------------------------------------
// Fused QKV GEMM (R17, proven): A DMA double-buffered, B coalesced reg-staged.
// K/V outputs in attention-staging tile layout:
//   K: [b][h][kt][u=d/8][k32][d%8]   V: [b][h][kt][ku=k/8][d96][k%8]
// ---------------------------------------------------------------------------
__global__ __launch_bounds__(256)
void gemm_qkv(const bf16* __restrict__ A,
              const float* __restrict__ Wq, const float* __restrict__ Wk,
              const float* __restrict__ Wv,
              const float* __restrict__ bq, const float* __restrict__ bk,
              const float* __restrict__ bv,
              bf16* __restrict__ Qo, bf16* __restrict__ Ka,
              bf16* __restrict__ Va) {
  constexpr int K = 768;
  __shared__ __align__(16) bf16 As[2][128 * 32];
  __shared__ __align__(16) bf16 Bs[128 * 32];

  const int tid  = threadIdx.x;
  const int wave = tid >> 6;
  const int lane = tid & 63;
  const int l15  = lane & 15;
  const int q4   = lane >> 4;
  const int wr   = wave >> 1;
  const int wc   = wave & 1;
  const int sel  = blockIdx.x / 6;
  const int cb0  = (blockIdx.x % 6) * 128;
  const int rb0  = blockIdx.y * 128;

  const float* W   = (sel == 0) ? Wq : (sel == 1) ? Wk : Wv;
  const float* bia = (sel == 0) ? bq : (sel == 1) ? bk : bv;

  const int ar0 = tid >> 2,         akc0 = (tid & 3) << 3;
  const int ar1 = ar0 + 64,         akc1 = akc0;

  fx4 acc[4][4];
#pragma unroll
  for (int i = 0; i < 4; i++)
#pragma unroll
    for (int j = 0; j < 4; j++) acc[i][j] = (fx4){0.f, 0.f, 0.f, 0.f};

  gload_lds16(&A[(size_t)(rb0 + ar0) * K + akc0], &As[0][wave * 512]);
  gload_lds16(&A[(size_t)(rb0 + ar1) * K + akc1], &As[0][(wave + 4) * 512]);

  int cur = 0;
  for (int k0 = 0; k0 < K; k0 += 32, cur ^= 1) {
    const float* wp0 = W + (size_t)(cb0 + ar0) * K + k0 + akc0;
    const float* wp1 = W + (size_t)(cb0 + ar1) * K + k0 + akc1;
    const float4 b0a = *(const float4*)wp0;
    const float4 b0b = *(const float4*)(wp0 + 4);
    const float4 b1a = *(const float4*)wp1;
    const float4 b1b = *(const float4*)(wp1 + 4);
    __asm__ __volatile__("" ::: "memory");

    const int kn = (k0 + 32 < K) ? k0 + 32 : k0;
    gload_lds16(&A[(size_t)(rb0 + ar0) * K + kn + akc0],
                &As[cur ^ 1][wave * 512]);
    gload_lds16(&A[(size_t)(rb0 + ar1) * K + kn + akc1],
                &As[cur ^ 1][(wave + 4) * 512]);
    __asm__ __volatile__("" ::: "memory");

    bf16x8 pb0, pb1;
    pb0[0] = (bf16)b0a.x; pb0[1] = (bf16)b0a.y;
    pb0[2] = (bf16)b0a.z; pb0[3] = (bf16)b0a.w;
    pb0[4] = (bf16)b0b.x; pb0[5] = (bf16)b0b.y;
    pb0[6] = (bf16)b0b.z; pb0[7] = (bf16)b0b.w;
    pb1[0] = (bf16)b1a.x; pb1[1] = (bf16)b1a.y;
    pb1[2] = (bf16)b1a.z; pb1[3] = (bf16)b1a.w;
    pb1[4] = (bf16)b1b.x; pb1[5] = (bf16)b1b.y;
    pb1[6] = (bf16)b1b.z; pb1[7] = (bf16)b1b.w;
    *(bf16x8*)&Bs[ar0 * 32 + akc0] = pb0;
    *(bf16x8*)&Bs[ar1 * 32 + akc1] = pb1;

    barrier_nodrain();

    bf16x8 a[4], b[4];
#pragma unroll
    for (int i = 0; i < 4; i++)
      a[i] = *(const bf16x8*)&As[cur][(wr * 64 + i * 16 + l15) * 32 + q4 * 8];
#pragma unroll
    for (int j = 0; j < 4; j++)
      b[j] = *(const bf16x8*)&Bs[(wc * 64 + j * 16 + l15) * 32 + q4 * 8];
#pragma unroll
    for (int i = 0; i < 4; i++)
#pragma unroll
      for (int j = 0; j < 4; j++)
        acc[i][j] = MFMA16(a[i], b[j], acc[i][j]);

    barrier_nodrain();
  }

  const int cb = cb0 + wc * 64;
  const int rb = rb0 + wr * 64;
#pragma unroll
  for (int j = 0; j < 4; j++) {
    const int o  = cb + j * 16 + l15;
    const float bj = bia[o];
    const int hh = o / 96;
    const int dd = o - hh * 96;
#pragma unroll
    for (int i = 0; i < 4; i++) {
      const int r0 = rb + i * 16 + q4 * 4;
      if (sel == 2) {
        const int bb = r0 >> 11;
        const int n2 = r0 & 2047;
        const size_t flat =
            ((size_t)((bb * 8 + hh) * 64 + (n2 >> 5))) * 3072 +
            ((n2 >> 3) & 3) * 768 + dd * 8 + (n2 & 7);
        bf16x4 pk;
#pragma unroll
        for (int r = 0; r < 4; r++) pk[r] = (bf16)(acc[i][j][r] + bj);
        *(bf16x4*)&Va[flat] = pk;
      } else if (sel == 1) {
        const int u  = dd >> 3;
        const int de = dd & 7;
#pragma unroll
        for (int r = 0; r < 4; r++) {
          const int n  = r0 + r;
          const int bb = n >> 11;
          const int n2 = n & 2047;
          const size_t flat =
              ((size_t)((bb * 8 + hh) * 64 + (n2 >> 5))) * 3072 +
              u * 256 + (n2 & 31) * 8 + de;
          Ka[flat] = (bf16)(acc[i][j][r] + bj);
        }
      } else {
#pragma unroll
        for (int r = 0; r < 4; r++)
          Qo[(size_t)(r0 + r) * 768 + o] = (bf16)(acc[i][j][r] + bj);
      }
    }
  }
}

// ---------------------------------------------------------------------------
// Output projection: out[M,768] fp32 = AO bf16 @ Wo^T + bo (R17, proven).
// ---------------------------------------------------------------------------
__global__ __launch_bounds__(256)
void gemm_o(const bf16* __restrict__ A, const float* __restrict__ W,
            const float* __restrict__ bias, float* __restrict__ C) {
  constexpr int K = 768;
  __shared__ __align__(16) bf16 As[2][128 * 32];
  __shared__ __align__(16) bf16 Bs[128 * 32];

  const int tid  = threadIdx.x;
  const int wave = tid >> 6;
  const int lane = tid & 63;
  const int l15  = lane & 15;
  const int q4   = lane >> 4;
  const int wr   = wave >> 1;
  const int wc   = wave & 1;
  const int rb0  = blockIdx.y * 128;
  const int cb0  = blockIdx.x * 128;

  const int ar0 = tid >> 2,         akc0 = (tid & 3) << 3;
  const int ar1 = ar0 + 64,         akc1 = akc0;

  fx4 acc[4][4];
#pragma unroll
  for (int i = 0; i < 4; i++)
#pragma unroll
    for (int j = 0; j < 4; j++) acc[i][j] = (fx4){0.f, 0.f, 0.f, 0.f};

  gload_lds16(&A[(size_t)(rb0 + ar0) * K + akc0], &As[0][wave * 512]);
  gload_lds16(&A[(size_t)(rb0 + ar1) * K + akc1], &As[0][(wave + 4) * 512]);

  int cur = 0;
  for (int k0 = 0; k0 < K; k0 += 32, cur ^= 1) {
    const float* wp0 = W + (size_t)(cb0 + ar0) * K + k0 + akc0;
    const float* wp1 = W + (size_t)(cb0 + ar1) * K + k0 + akc1;
    const float4 b0a = *(const float4*)wp0;
    const float4 b0b = *(const float4*)(wp0 + 4);
    const float4 b1a = *(const float4*)wp1;
    const float4 b1b = *(const float4*)(wp1 + 4);
    __asm__ __volatile__("" ::: "memory");

    const int kn = (k0 + 32 < K) ? k0 + 32 : k0;
    gload_lds16(&A[(size_t)(rb0 + ar0) * K + kn + akc0],
                &As[cur ^ 1][wave * 512]);
    gload_lds16(&A[(size_t)(rb0 + ar1) * K + kn + akc1],
                &As[cur ^ 1][(wave + 4) * 512]);
    __asm__ __volatile__("" ::: "memory");

    bf16x8 pb0, pb1;
    pb0[0] = (bf16)b0a.x; pb0[1] = (bf16)b0a.y;
    pb0[2] = (bf16)b0a.z; pb0[3] = (bf16)b0a.w;
    pb0[4] = (bf16)b0b.x; pb0[5] = (bf16)b0b.y;
    pb0[6] = (bf16)b0b.z; pb0[7] = (bf16)b0b.w;
    pb1[0] = (bf16)b1a.x; pb1[1] = (bf16)b1a.y;
    pb1[2] = (bf16)b1a.z; pb1[3] = (bf16)b1a.w;
    pb1[4] = (bf16)b1b.x; pb1[5] = (bf16)b1b.y;
    pb1[6] = (bf16)b1b.z; pb1[7] = (bf16)b1b.w;
    *(bf16x8*)&Bs[ar0 * 32 + akc0] = pb0;
    *(bf16x8*)&Bs[ar1 * 32 + akc1] = pb1;

    barrier_nodrain();

    bf16x8 a[4], b[4];
#pragma unroll
    for (int i = 0; i < 4; i++)
      a[i] = *(const bf16x8*)&As[cur][(wr * 64 + i * 16 + l15) * 32 + q4 * 8];
#pragma unroll
    for (int j = 0; j < 4; j++)
      b[j] = *(const bf16x8*)&Bs[(wc * 64 + j * 16 + l15) * 32 + q4 * 8];
#pragma unroll
    for (int i = 0; i < 4; i++)
#pragma unroll
      for (int j = 0; j < 4; j++)
        acc[i][j] = MFMA16(a[i], b[j], acc[i][j]);

    barrier_nodrain();
  }

  const int cb = cb0 + wc * 64;
  const int rb = rb0 + wr * 64;
#pragma unroll
  for (int j = 0; j < 4; j++) {
    const int o  = cb + j * 16 + l15;
    const float bj = bias[o];
#pragma unroll
    for (int i = 0; i < 4; i++) {
      const int r0 = rb + i * 16 + q4 * 4;
#pragma unroll
      for (int r = 0; r < 4; r++)
        C[(size_t)(r0 + r) * 768 + o] = acc[i][j][r] + bj;
    }
  }
}

// ---------------------------------------------------------------------------
// Attention, softmax over HEADS (dim=1), / sqrt(768).
// R19 = R15 structure (R18 reorder REVERTED: it regressed −5 µs; within-wave
// ILP already covered QK^T||softmax) + LDS-instruction-count attack.
// Accounting that motivated this: 5400 cyc/iter, of which ~3800 = LDS pipe
// (per wave: 16 b128 + 48 b32). Changes:
//  1. SWAPPED QK^T (mfma(bk,aq) -> E^T): A/B frag layouts are lane-identical
//     so loads unchanged; lane's 4 acc values become 4 consecutive k ->
//     scatter = 4 x b128 (was 16 x b32). Stride 260 keeps it ~2-way.
//  2. k-pair softmax: thread owns (q, 2 adjacent k): 8 x b64 reads
//     (was 16 x b32), same 16 exps.
//  3. bf16 Pbuf[h][q][k pad 40] returns (R10/R12-proven banking): softmax
//     writes 8 x u32 packed bf16 pairs; PV A-frag = 2 x b128 (was 4) and
//     the f32->bf16 pack VALU disappears. P in bf16 = same numerics as
//     R0-R14 (absmax was identical). Also structurally removes the old
//     next-iter-scatter vs Ebuf-P-read timing race.
// New per-wave count: 18 b128 + 8 b64 + 8 u32 (~310 cyc, -35%).
// LDS: Kbuf 48 + Vbuf 48 + Ebuf 32.5 + Pbuf 20 = 148.5 KB (<160, 1 blk/CU).
// vmcnt discipline identical to R15. setprio kept around MFMA clusters.
// ---------------------------------------------------------------------------
__global__ __launch_bounds__(512, 1)
void attn_kernel(const bf16* Q, const bf16* __restrict__ Ka,
                 const bf16* __restrict__ Va, bf16* AO) {
  __shared__ __align__(16) bf16  Kbuf[8 * 3072];   // [h][u12][k32][8] 48 KB
  __shared__ __align__(16) bf16  Vbuf[8 * 3072];   // [h][ku4][d96][8] 48 KB
  __shared__ __align__(16) float Ebuf[32 * 260];   // [q][h*32+k]    32.5 KB
  __shared__ __align__(16) bf16  Pbuf[8 * 32 * 40]; // [h][q][k pad40] 20 KB

  const int tid  = threadIdx.x;
  const int h    = tid >> 6;
  const int lane = tid & 63;
  const int l15  = lane & 15;
  const int q4   = lane >> 4;
  const int b    = blockIdx.x >> 6;
  const int qt   = blockIdx.x & 63;
  const int qrow0 = b * 2048 + qt * 32;

  // Persistent Q fragments: 2 q-16tiles x 3 d-chunks.
  bf16x8 aq[2][3];
#pragma unroll
  for (int i = 0; i < 2; i++)
#pragma unroll
    for (int c = 0; c < 3; c++)
      aq[i][c] = *(const bf16x8*)
          &Q[(size_t)(qrow0 + i * 16 + l15) * 768 + h * 96 + c * 32 + q4 * 8];

  fx4 o[2][6];
#pragma unroll
  for (int i = 0; i < 2; i++)
#pragma unroll
    for (int j = 0; j < 6; j++) o[i][j] = (fx4){0.f, 0.f, 0.f, 0.f};

  const bf16* Kt0 = Ka + (size_t)(b * 8 + h) * 64 * 3072;
  const bf16* Vt0 = Va + (size_t)(b * 8 + h) * 64 * 3072;
  bf16* Kl = &Kbuf[h * 3072];
  bf16* Vl = &Vbuf[h * 3072];

  auto stageK = [&](int kt) {
    const bf16* src = Kt0 + (size_t)kt * 3072 + lane * 8;
#pragma unroll
    for (int t = 0; t < 6; t++)
      gload_lds16(src + t * 512, Kl + t * 512);
  };
  auto stageV = [&](int kt) {
    const bf16* src = Vt0 + (size_t)kt * 3072 + lane * 8;
#pragma unroll
    for (int t = 0; t < 6; t++)
      gload_lds16(src + t * 512, Vl + t * 512);
  };

  stageK(0);
  stageV(0);

  for (int kt = 0; kt < 64; kt++) {
    const int kn = (kt + 1 < 64) ? kt + 1 : 63;

    // --- K(kt) ready? (allow V(kt)'s 6 loads outstanding) ---
    wait_vm6();

    // K frags: k=j*16+l15 rows, d-unit=(c*4+q4) -> 16 B/lane, 2-way.
    bf16x8 bk[2][3];
#pragma unroll
    for (int j = 0; j < 2; j++)
#pragma unroll
      for (int c = 0; c < 3; c++)
        bk[j][c] =
            *(const bf16x8*)&Kl[(c * 4 + q4) * 256 + (j * 16 + l15) * 8];

    // K region free once reads retire; DMA next K tile.
    wait_lgkm0();
    stageK(kn);

    // E^T = K Q^T : swapped operands. e2[j][i]: lane owns q = i*16 + l15,
    // k = j*16 + q4*4 + r (4 consecutive k per accumulator).
    fx4 e2[2][2];
    e2[0][0] = e2[0][1] = e2[1][0] = e2[1][1] = (fx4){0.f, 0.f, 0.f, 0.f};
    __builtin_amdgcn_s_setprio(1);
#pragma unroll
    for (int c = 0; c < 3; c++)
#pragma unroll
      for (int j = 0; j < 2; j++) {
        e2[j][0] = MFMA16(bk[j][c], aq[0][c], e2[j][0]);
        e2[j][1] = MFMA16(bk[j][c], aq[1][c], e2[j][1]);
      }
    __builtin_amdgcn_s_setprio(0);

    // Vectorized scatter: one b128 per (i,j) -> Ebuf[q*260 + h*32 + k0].
#pragma unroll
    for (int i = 0; i < 2; i++)
#pragma unroll
      for (int j = 0; j < 2; j++)
        *(fx4*)&Ebuf[(i * 16 + l15) * 260 + h * 32 + j * 16 + q4 * 4] =
            e2[j][i];
    barrier_nodrain();

    // Softmax over heads. Thread owns (q, 2 adjacent k): 8 b64 reads,
    // 8 u32 packed bf16 writes to Pbuf[h][q][k].
    {
      const int q  = tid >> 4;          // 0..31
      const int k2 = (tid & 15) << 1;   // 0,2,...,30
      const float* row = &Ebuf[q * 260 + k2];
      fx2 v[8];
#pragma unroll
      for (int hh = 0; hh < 8; hh++) v[hh] = *(const fx2*)&row[hh * 32];
      fx2 m = v[0];
#pragma unroll
      for (int hh = 1; hh < 8; hh++) {
        m[0] = fmaxf(m[0], v[hh][0]);
        m[1] = fmaxf(m[1], v[hh][1]);
      }
      fx2 sm = (fx2){0.f, 0.f};
#pragma unroll
      for (int hh = 0; hh < 8; hh++) {
        v[hh][0] = __expf(v[hh][0] - m[0]);
        v[hh][1] = __expf(v[hh][1] - m[1]);
        sm += v[hh];
      }
      const float inv0 = 1.0f / (sm[0] * 27.712812921102035f);  // / sqrt(768)
      const float inv1 = 1.0f / (sm[1] * 27.712812921102035f);
#pragma unroll
      for (int hh = 0; hh < 8; hh++) {
        bf16x2 pk;
        pk[0] = (bf16)(v[hh][0] * inv0);
        pk[1] = (bf16)(v[hh][1] * inv1);
        *(bf16x2*)&Pbuf[hh * 1280 + q * 40 + k2] = pk;
      }
    }
    barrier_nodrain();

    // --- V(kt) ready? (allow K(kn)'s 6 loads outstanding) ---
    wait_vm6();

    // V frags: d=j2*16+l15, k-unit=q4 -> 16 B/lane, 2-way.
    bf16x8 bv[6];
#pragma unroll
    for (int j2 = 0; j2 < 6; j2++)
      bv[j2] = *(const bf16x8*)&Vl[q4 * 768 + (j2 * 16 + l15) * 8];

    // P A-frags direct from bf16 Pbuf: q=i*16+l15, k=q4*8..+7 -> 1 b128.
    bf16x8 ap[2];
#pragma unroll
    for (int i = 0; i < 2; i++)
      ap[i] = *(const bf16x8*)&Pbuf[h * 1280 + (i * 16 + l15) * 40 + q4 * 8];

    // V region free; DMA next V tile.
    wait_lgkm0();
    stageV(kn);

    // O += P @ V.
    __builtin_amdgcn_s_setprio(1);
#pragma unroll
    for (int j2 = 0; j2 < 6; j2++) {
      o[0][j2] = MFMA16(ap[0], bv[j2], o[0][j2]);
      o[1][j2] = MFMA16(ap[1], bv[j2], o[1][j2]);
    }
    __builtin_amdgcn_s_setprio(0);
  }

  // Drain outstanding DMA before exit/stores.
  __builtin_amdgcn_s_waitcnt(0x0070);

  // Write AO[qrow0 + q][h*96 + d]
#pragma unroll
  for (int i = 0; i < 2; i++)
#pragma unroll
    for (int j2 = 0; j2 < 6; j2++)
#pragma unroll
      for (int r = 0; r < 4; r++)
        AO[(size_t)(qrow0 + i * 16 + q4 * 4 + r) * 768 + h * 96 + j2 * 16 + l15] =
            (bf16)(o[i][j2][r]);
}

// ---------------------------------------------------------------------------
// Memory plan: d_out = xb + Ka (both dead before gemm_o overwrites d_out).
// ws = Q + Va (25.2 MB). AO aliases Q.
// ---------------------------------------------------------------------------
extern "C" void kernel_launch(void* const* d_in, const int* in_sizes, int n_in,
                              void* d_out, int out_size, void* d_ws,
                              size_t ws_size, hipStream_t stream) {
  const float* x  = (const float*)d_in[0];
  const float* Wq = (const float*)d_in[1];
  const float* bq = (const float*)d_in[2];
  const float* Wk = (const float*)d_in[3];
  const float* bk = (const float*)d_in[4];
  const float* Wv = (const float*)d_in[5];
  const float* bv = (const float*)d_in[6];
  const float* Wo = (const float*)d_in[7];
  const float* bo = (const float*)d_in[8];

  const size_t MN = (size_t)8192 * 768;
  bf16* xb = (bf16*)d_out;
  bf16* Ka = xb + MN;
  bf16* Q  = (bf16*)d_ws;
  bf16* Va = Q + MN;
  bf16* AO = Q;  // aliases Q

  cvt_x_kernel<<<6144, 256, 0, stream>>>(x, xb);
  dim3 qkvgrid(18, 64);
  gemm_qkv<<<qkvgrid, 256, 0, stream>>>(xb, Wq, Wk, Wv, bq, bk, bv, Q, Ka, Va);
  attn_kernel<<<256, 512, 0, stream>>>(Q, Ka, Va, AO);
  dim3 ogrid(6, 64);
  gemm_o<<<ogrid, 256, 0, stream>>>(AO, Wo, bo, (float*)d_out);
}